// Round 4
// baseline (61.176 us; speedup 1.0000x reference)
//
#include <hip/hip_runtime.h>
#include <hip/hip_bf16.h>
#include <math.h>

#define KC 32
#define DC 128
#define QC 16
#define NPTS 20000

// ws layout (bytes):
//   C2p[32] f32      @ 0
//   BT_HI[544*128] s @ 128
//   BT_LO[544*128] s @ 139392
//   XH[20000*128] s  @ 278656
//   XL[20000*128] s  @ 5398656
//   S2[20000] f32    @ 10518656
#define WS_C2P_B 0
#define WS_BTH_B 128
#define WS_BTL_B 139392
#define WS_XH_B  278656
#define WS_XL_B  5398656
#define WS_S2_B  10518656

typedef __attribute__((ext_vector_type(8))) short bf16x8;
typedef __attribute__((ext_vector_type(4))) float f32x4;

// round-to-nearest-even bf16 split
static __device__ __forceinline__ short f2bf(float x) {
    union { float f; unsigned u; } v; v.f = x;
    unsigned r = v.u + 0x7fffu + ((v.u >> 16) & 1u);
    return (short)(r >> 16);
}
static __device__ __forceinline__ float bf2f(short h) {
    union { unsigned u; float f; } v; v.u = ((unsigned)(unsigned short)h) << 16;
    return v.f;
}

// ---------------------------------------------------------------------------
// Kernel 1 (fused prep): blocks 0..31 do per-component precompute (Woodbury
// constants -> G rows, w' row, C2'); blocks 32..188 convert X rows to bf16
// hi/lo (rounding split) and compute s2[n] = x^T Psi'^-1 x.
// ---------------------------------------------------------------------------
__global__ __launch_bounds__(256) void mfa_prep(
    const float* __restrict__ X, const float* __restrict__ log_pi,
    const float* __restrict__ mu, const float* __restrict__ Lam,
    const float* __restrict__ log_psi,
    float* __restrict__ c2p, short* __restrict__ btH, short* __restrict__ btL,
    short* __restrict__ xH, short* __restrict__ xL, float* __restrict__ s2g)
{
    int t = threadIdx.x;
    if (blockIdx.x >= KC) {
        // ---- conversion path ----
        int xb = blockIdx.x - KC;          // 0..156
        int cseg = t & 15, rloc = t >> 4;
        int c0 = cseg * 8;
        float is[8];
#pragma unroll
        for (int j = 0; j < 8; j++) {
            float psi = expf(log_psi[c0 + j]) + 1e-5f + 1e-4f;
            is[j] = 1.0f / psi;
        }
#pragma unroll 1
        for (int p = 0; p < 8; p++) {
            int r = xb*128 + p*16 + rloc;
            if (r < NPTS) {
                float xs[8];
                const float* xp = X + (size_t)r*DC + c0;
                *(float4*)&xs[0] = *(const float4*)xp;
                *(float4*)&xs[4] = *(const float4*)(xp + 4);
                bf16x8 hv, lv;
                float s2 = 0.f;
#pragma unroll
                for (int j = 0; j < 8; j++) {
                    short hi = f2bf(xs[j]);
                    float hf = bf2f(hi);
                    hv[j] = hi;
                    lv[j] = f2bf(xs[j] - hf);
                    s2 = fmaf(xs[j]*is[j], xs[j], s2);
                }
                *(bf16x8*)(xH + (size_t)r*DC + c0) = hv;
                *(bf16x8*)(xL + (size_t)r*DC + c0) = lv;
                s2 += __shfl_xor(s2, 1, 16);
                s2 += __shfl_xor(s2, 2, 16);
                s2 += __shfl_xor(s2, 4, 16);
                s2 += __shfl_xor(s2, 8, 16);
                if (cseg == 0) s2g[r] = s2;
            }
        }
        return;
    }
    // ---- per-component path ----
    int k = blockIdx.x;
    __shared__ float invpsiS[DC], muS[DC];
    __shared__ float lamR[DC*17];
    __shared__ float MS[QC*QC], LSm[QC*QC];
    __shared__ float invDS[QC];
    __shared__ float GT[QC*129];
    __shared__ float hS[QC];
    __shared__ float redS[4];
    __shared__ float hhS, ldS;

    float lp = 0.f, ipm = 0.f;
    if (t < DC) {
        float psi = expf(log_psi[t]) + 1e-5f + 1e-4f;
        float ip = 1.0f / psi;
        invpsiS[t] = ip;
        lp = logf(psi);
        float m = mu[k*DC + t];
        muS[t] = m;
        ipm = ip*m*m;
    }
    __syncthreads();
    for (int e = t; e < DC*QC; e += 256) {
        int d = e >> 4, q = e & 15;
        lamR[d*17 + q] = Lam[k*DC*QC + e];
    }
    __syncthreads();
    {   // M = I + Lam^T diag(invpsi) Lam
        int q = t >> 4, r = t & 15;
        float s = (q == r) ? 1.0f : 0.0f;
        for (int d = 0; d < DC; d++)
            s = fmaf(lamR[d*17 + q] * invpsiS[d], lamR[d*17 + r], s);
        MS[q*QC + r] = s;
    }
    __syncthreads();
    if (t < QC) {       // 16-lane shuffle Cholesky; lane i owns row i
        float m[QC], lrow[QC];
#pragma unroll
        for (int j = 0; j < QC; j++) m[j] = MS[t*QC + j];
#pragma unroll
        for (int j = 0; j < QC; j++) {
            float piv = __shfl(m[j], j, 16);
            float ljj = sqrtf(piv);
            float lij = m[j] / ljj;
            lrow[j] = lij;
#pragma unroll
            for (int r = j + 1; r < QC; r++)
                m[r] = fmaf(-lij, __shfl(lij, r, 16), m[r]);
        }
#pragma unroll
        for (int j = 0; j < QC; j++) LSm[t*QC + j] = lrow[j];
        invDS[t] = 1.0f / lrow[t];
        float ld = 2.0f * logf(lrow[t]);
        ld += __shfl_xor(ld, 1, 16);
        ld += __shfl_xor(ld, 2, 16);
        ld += __shfl_xor(ld, 4, 16);
        ld += __shfl_xor(ld, 8, 16);
        if (t == 0) ldS = ld;
    }
    __syncthreads();
    float g[QC];
    if (t < DC) {       // forward solve: column t of G
        float ip = invpsiS[t];
        float b[QC];
#pragma unroll
        for (int q = 0; q < QC; q++) b[q] = lamR[t*17 + q] * ip;
#pragma unroll
        for (int i = 0; i < QC; i++) {
            float s = b[i];
#pragma unroll
            for (int x = 0; x < i; x++)
                s = fmaf(-LSm[i*QC + x], g[x], s);
            g[i] = s * invDS[i];
        }
#pragma unroll
        for (int q = 0; q < QC; q++) {
            GT[q*129 + t] = g[q];
            short hi = f2bf(g[q]);
            float hf = bf2f(hi);
            btH[(k*QC + q)*DC + t] = hi;
            btL[(k*QC + q)*DC + t] = f2bf(g[q] - hf);
        }
    }
    __syncthreads();
    if (t < QC) {       // h = G mu
        float s = 0.f;
        for (int d = 0; d < DC; d++)
            s = fmaf(GT[t*129 + d], muS[d], s);
        hS[t] = s;
        float hh = s*s;
        hh += __shfl_xor(hh, 1, 16);
        hh += __shfl_xor(hh, 2, 16);
        hh += __shfl_xor(hh, 4, 16);
        hh += __shfl_xor(hh, 8, 16);
        if (t == 0) hhS = hh;
    }
    {
        float a = lp, b2 = ipm;
#pragma unroll
        for (int off = 1; off < 64; off <<= 1) {
            a  += __shfl_xor(a, off, 64);
            b2 += __shfl_xor(b2, off, 64);
        }
        if (t == 0)  { redS[0] = a; redS[1] = b2; }
        if (t == 64) { redS[2] = a; redS[3] = b2; }
    }
    __syncthreads();
    if (t < DC) {       // w' = invpsi*mu - G^T h
        float gh = 0.f;
#pragma unroll
        for (int q = 0; q < QC; q++) gh = fmaf(g[q], hS[q], gh);
        float wp = invpsiS[t]*muS[t] - gh;
        short hi = f2bf(wp);
        float hf = bf2f(hi);
        btH[(512 + k)*DC + t] = hi;
        btL[(512 + k)*DC + t] = f2bf(wp - hf);
    }
    if (t == 0) {
        const float log2pi = 1.8378770664093453f;
        float slp = redS[0] + redS[2];
        float tv  = redS[1] + redS[3];
        c2p[k] = log_pi[k]
            - 0.5f*((float)DC*log2pi + slp + ldS + tv) + 0.5f*hhS;
    }
}

// ---------------------------------------------------------------------------
// Kernel 2: MFMA GEMM. grid (157,4); block 256 = 4 waves; y-block owns 8
// components (128 G rows + 8 w' rows in LDS, XOR-swizzled); each wave owns
// 2 M-tiles (32 rows) so every B ds_read feeds 6 MFMAs. A is precomputed
// bf16 hi/lo from ws. Rows 136..143 of LDS read as garbage into pacc cols
// 8..15 which are never extracted (in-bounds, col-independent).
// ---------------------------------------------------------------------------
#define LROWSP 144
#define LH (LROWSP*256)      // 36864 bytes per hi/lo plane

__global__ __launch_bounds__(256, 2) void mfa_gemm(
    const short* __restrict__ xH, const short* __restrict__ xL,
    const float* __restrict__ s2g, const float* __restrict__ c2p,
    const short* __restrict__ btH, const short* __restrict__ btL,
    float* __restrict__ out)
{
    __shared__ __align__(16) char lds[2*LH];     // 73728 B
    int t = threadIdx.x, yb = blockIdx.y;

    for (int s = t; s < 136*16; s += 256) {
        int row = s >> 4, seg = s & 15;
        int gr = (row < 128) ? (yb*128 + row) : (512 + yb*8 + (row - 128));
        unsigned bo = ((unsigned)(row*256 + seg*16)) ^ ((unsigned)(row & 7) << 4);
        *(bf16x8*)(lds + bo)      = *(const bf16x8*)(btH + gr*DC + seg*8);
        *(bf16x8*)(lds + LH + bo) = *(const bf16x8*)(btL + gr*DC + seg*8);
    }

    int l = t & 63, w = t >> 6;
    int m16 = l & 15, g4 = l >> 4;
    int rb0 = blockIdx.x*128 + w*16;

    bf16x8 aH[2][4], aL[2][4];
    float s2p[2];
#pragma unroll
    for (int mt = 0; mt < 2; mt++) {
        int xr = min(rb0 + mt*64 + m16, NPTS - 1);
        const short* ph = xH + (size_t)xr*DC + g4*8;
        const short* pl = xL + (size_t)xr*DC + g4*8;
#pragma unroll
        for (int ks = 0; ks < 4; ks++) {
            aH[mt][ks] = *(const bf16x8*)(ph + ks*32);
            aL[mt][ks] = *(const bf16x8*)(pl + ks*32);
        }
        s2p[mt] = s2g[xr];
    }
    __syncthreads();

    f32x4 acc[2][9];
#pragma unroll
    for (int mt = 0; mt < 2; mt++)
#pragma unroll
        for (int nt = 0; nt < 9; nt++)
            acc[mt][nt] = (f32x4){0.f, 0.f, 0.f, 0.f};

#pragma unroll
    for (int nt = 0; nt < 9; nt++) {
        int row = nt*16 + m16;
        unsigned rbse = (unsigned)row << 8;
        unsigned sw = (unsigned)(row & 7) << 4;
#pragma unroll
        for (int ks = 0; ks < 4; ks++) {
            unsigned bo = (rbse + (unsigned)((ks*32 + g4*8)*2)) ^ sw;
            bf16x8 bh = *(const bf16x8*)(lds + bo);
            bf16x8 bl = *(const bf16x8*)(lds + LH + bo);
            acc[0][nt] = __builtin_amdgcn_mfma_f32_16x16x32_bf16(aH[0][ks], bh, acc[0][nt], 0, 0, 0);
            acc[1][nt] = __builtin_amdgcn_mfma_f32_16x16x32_bf16(aH[1][ks], bh, acc[1][nt], 0, 0, 0);
            acc[0][nt] = __builtin_amdgcn_mfma_f32_16x16x32_bf16(aL[0][ks], bh, acc[0][nt], 0, 0, 0);
            acc[1][nt] = __builtin_amdgcn_mfma_f32_16x16x32_bf16(aL[1][ks], bh, acc[1][nt], 0, 0, 0);
            acc[0][nt] = __builtin_amdgcn_mfma_f32_16x16x32_bf16(aH[0][ks], bl, acc[0][nt], 0, 0, 0);
            acc[1][nt] = __builtin_amdgcn_mfma_f32_16x16x32_bf16(aH[1][ks], bl, acc[1][nt], 0, 0, 0);
        }
    }

#pragma unroll
    for (int mt = 0; mt < 2; mt++) {
#pragma unroll
        for (int nt = 0; nt < 8; nt++) {
            float c2v = c2p[yb*8 + nt];
#pragma unroll
            for (int j = 0; j < 4; j++) {
                float v = acc[mt][nt][j]*acc[mt][nt][j];
                v += __shfl_xor(v, 1, 64);
                v += __shfl_xor(v, 2, 64);
                v += __shfl_xor(v, 4, 64);
                v += __shfl_xor(v, 8, 64);
                float pv  = __shfl(acc[mt][8][j], (l & 48) | nt, 64);
                float s2j = __shfl(s2p[mt], (l & 48) | (g4*4 + j), 64);
                float lr = c2v + pv - 0.5f*s2j + 0.5f*v;
                int row = rb0 + mt*64 + g4*4 + j;
                if (m16 == 0 && row < NPTS)
                    out[(size_t)row*KC + yb*8 + nt] = lr;
            }
        }
    }
}

// ---------------------------------------------------------------------------
// Kernel 3: in-place logsumexp normalize + log-likelihood output.
// ---------------------------------------------------------------------------
__global__ __launch_bounds__(256) void mfa_norm(float* __restrict__ out)
{
    int n = blockIdx.x * 256 + threadIdx.x;
    if (n >= NPTS) return;
    float lr[KC];
#pragma unroll
    for (int i = 0; i < 8; i++)
        *(float4*)&lr[i*4] = *(const float4*)(out + (size_t)n*KC + i*4);
    float m = -1e30f;
#pragma unroll
    for (int k = 0; k < KC; k++) m = fmaxf(m, lr[k]);
    float s = 0.0f;
#pragma unroll
    for (int k = 0; k < KC; k++) s += expf(lr[k] - m);
    float ll = m + logf(s);
#pragma unroll
    for (int k = 0; k < KC; k++) lr[k] -= ll;
#pragma unroll
    for (int i = 0; i < 8; i++)
        *(float4*)(out + (size_t)n*KC + i*4) = *(const float4*)&lr[i*4];
    out[(size_t)NPTS*KC + n] = ll;
}

extern "C" void kernel_launch(void* const* d_in, const int* in_sizes, int n_in,
                              void* d_out, int out_size, void* d_ws, size_t ws_size,
                              hipStream_t stream)
{
    const float* X       = (const float*)d_in[0];
    const float* log_pi  = (const float*)d_in[1];
    const float* mu      = (const float*)d_in[2];
    const float* Lam     = (const float*)d_in[3];
    const float* log_psi = (const float*)d_in[4];
    float* out = (float*)d_out;
    char* wsb = (char*)d_ws;
    float* c2p = (float*)(wsb + WS_C2P_B);
    short* btH = (short*)(wsb + WS_BTH_B);
    short* btL = (short*)(wsb + WS_BTL_B);
    short* xH  = (short*)(wsb + WS_XH_B);
    short* xL  = (short*)(wsb + WS_XL_B);
    float* s2g = (float*)(wsb + WS_S2_B);

    hipLaunchKernelGGL(mfa_prep, dim3(KC + 157), dim3(256), 0, stream,
                       X, log_pi, mu, Lam, log_psi, c2p, btH, btL, xH, xL, s2g);
    hipLaunchKernelGGL(mfa_gemm, dim3(157, 4), dim3(256), 0, stream,
                       xH, xL, s2g, c2p, btH, btL, out);
    hipLaunchKernelGGL(mfa_norm, dim3(79), dim3(256), 0, stream, out);
}

// Round 5
// 47.397 us; speedup vs baseline: 1.2907x; 1.2907x over previous
//
#include <hip/hip_runtime.h>
#include <hip/hip_bf16.h>
#include <math.h>

#define KC 32
#define DC 128
#define QC 16
#define NPTS 20000

// ws layout (bytes):
//   C2p[32] f32      @ 0
//   BT_HI[544*128] s @ 128
//   BT_LO[544*128] s @ 139392
//   XH[20000*128] s  @ 278656
//   XL[20000*128] s  @ 5398656
//   S2H[20000] f32   @ 10518656   (pre-scaled by 0.5)
#define WS_C2P_B 0
#define WS_BTH_B 128
#define WS_BTL_B 139392
#define WS_XH_B  278656
#define WS_XL_B  5398656
#define WS_S2_B  10518656

typedef __attribute__((ext_vector_type(8))) short bf16x8;
typedef __attribute__((ext_vector_type(4))) float f32x4;

// round-to-nearest-even bf16 split
static __device__ __forceinline__ short f2bf(float x) {
    union { float f; unsigned u; } v; v.f = x;
    unsigned r = v.u + 0x7fffu + ((v.u >> 16) & 1u);
    return (short)(r >> 16);
}
static __device__ __forceinline__ float bf2f(short h) {
    union { unsigned u; float f; } v; v.u = ((unsigned)(unsigned short)h) << 16;
    return v.f;
}

// ---------------------------------------------------------------------------
// Kernel 1 (fused prep): blocks 0..31 per-component Woodbury precompute
// (G rows scaled by 1/sqrt(2), w' row, C2'); blocks 32..345 convert 64 X rows
// each to bf16 hi/lo and store 0.5 * x^T Psi'^-1 x.
// ---------------------------------------------------------------------------
__global__ __launch_bounds__(256) void mfa_prep(
    const float* __restrict__ X, const float* __restrict__ log_pi,
    const float* __restrict__ mu, const float* __restrict__ Lam,
    const float* __restrict__ log_psi,
    float* __restrict__ c2p, short* __restrict__ btH, short* __restrict__ btL,
    short* __restrict__ xH, short* __restrict__ xL, float* __restrict__ s2g)
{
    int t = threadIdx.x;
    if (blockIdx.x >= KC) {
        // ---- conversion path: 64 rows per block ----
        int xb = blockIdx.x - KC;          // 0..313
        int cseg = t & 15, rloc = t >> 4;
        int c0 = cseg * 8;
        float is[8];
#pragma unroll
        for (int j = 0; j < 8; j++) {
            float psi = expf(log_psi[c0 + j]) + 1e-5f + 1e-4f;
            is[j] = 1.0f / psi;
        }
#pragma unroll
        for (int p = 0; p < 4; p++) {
            int r = xb*64 + p*16 + rloc;
            if (r < NPTS) {
                float xs[8];
                const float* xp = X + (size_t)r*DC + c0;
                *(float4*)&xs[0] = *(const float4*)xp;
                *(float4*)&xs[4] = *(const float4*)(xp + 4);
                bf16x8 hv, lv;
                float s2 = 0.f;
#pragma unroll
                for (int j = 0; j < 8; j++) {
                    short hi = f2bf(xs[j]);
                    float hf = bf2f(hi);
                    hv[j] = hi;
                    lv[j] = f2bf(xs[j] - hf);
                    s2 = fmaf(xs[j]*is[j], xs[j], s2);
                }
                *(bf16x8*)(xH + (size_t)r*DC + c0) = hv;
                *(bf16x8*)(xL + (size_t)r*DC + c0) = lv;
                s2 += __shfl_xor(s2, 1, 16);
                s2 += __shfl_xor(s2, 2, 16);
                s2 += __shfl_xor(s2, 4, 16);
                s2 += __shfl_xor(s2, 8, 16);
                if (cseg == 0) s2g[r] = 0.5f * s2;
            }
        }
        return;
    }
    // ---- per-component path ----
    int k = blockIdx.x;
    __shared__ float invpsiS[DC], muS[DC];
    __shared__ float lamR[DC*17];        // Lam[d][q]
    __shared__ float lamSc[DC*17];       // Lam[d][q]*invpsi[d]
    __shared__ float MS[QC*QC], LSm[QC*QC];
    __shared__ float invDS[QC];
    __shared__ float GT[QC*129];
    __shared__ float hS[QC];
    __shared__ float redS[4];
    __shared__ float hhS, ldS;

    float lp = 0.f, ipm = 0.f;
    if (t < DC) {
        float psi = expf(log_psi[t]) + 1e-5f + 1e-4f;
        float ip = 1.0f / psi;
        invpsiS[t] = ip;
        lp = logf(psi);
        float m = mu[k*DC + t];
        muS[t] = m;
        ipm = ip*m*m;
    }
    __syncthreads();
    for (int e = t; e < DC*QC; e += 256) {
        int d = e >> 4, q = e & 15;
        float lv = Lam[k*DC*QC + e];
        lamR[d*17 + q]  = lv;
        lamSc[d*17 + q] = lv * invpsiS[d];
    }
    __syncthreads();
    {   // M = I + Lam^T diag(invpsi) Lam
        int q = t >> 4, r = t & 15;
        float s0 = (q == r) ? 1.0f : 0.0f, s1 = 0.f, s2 = 0.f, s3 = 0.f;
#pragma unroll 1
        for (int d = 0; d < DC; d += 4) {
            s0 = fmaf(lamSc[(d+0)*17 + q], lamR[(d+0)*17 + r], s0);
            s1 = fmaf(lamSc[(d+1)*17 + q], lamR[(d+1)*17 + r], s1);
            s2 = fmaf(lamSc[(d+2)*17 + q], lamR[(d+2)*17 + r], s2);
            s3 = fmaf(lamSc[(d+3)*17 + q], lamR[(d+3)*17 + r], s3);
        }
        MS[q*QC + r] = (s0 + s1) + (s2 + s3);
    }
    __syncthreads();
    if (t < QC) {       // 16-lane shuffle Cholesky; lane i owns row i
        float m[QC], lrow[QC];
#pragma unroll
        for (int j = 0; j < QC; j++) m[j] = MS[t*QC + j];
#pragma unroll
        for (int j = 0; j < QC; j++) {
            float piv = __shfl(m[j], j, 16);
            float ljj = sqrtf(piv);
            float lij = m[j] / ljj;
            lrow[j] = lij;
#pragma unroll
            for (int r = j + 1; r < QC; r++)
                m[r] = fmaf(-lij, __shfl(lij, r, 16), m[r]);
        }
#pragma unroll
        for (int j = 0; j < QC; j++) LSm[t*QC + j] = lrow[j];
        invDS[t] = 1.0f / lrow[t];
        float ld = 2.0f * logf(lrow[t]);
        ld += __shfl_xor(ld, 1, 16);
        ld += __shfl_xor(ld, 2, 16);
        ld += __shfl_xor(ld, 4, 16);
        ld += __shfl_xor(ld, 8, 16);
        if (t == 0) ldS = ld;
    }
    __syncthreads();
    float g[QC];
    if (t < DC) {       // forward solve: column t of G
        float b[QC];
#pragma unroll
        for (int q = 0; q < QC; q++) b[q] = lamSc[t*17 + q];
#pragma unroll
        for (int i = 0; i < QC; i++) {
            float s = b[i];
#pragma unroll
            for (int x = 0; x < i; x++)
                s = fmaf(-LSm[i*QC + x], g[x], s);
            g[i] = s * invDS[i];
        }
        const float is2 = 0.70710678118654752f;
#pragma unroll
        for (int q = 0; q < QC; q++) {
            GT[q*129 + t] = g[q];
            float gs = g[q] * is2;                 // store G/sqrt(2)
            short hi = f2bf(gs);
            float hf = bf2f(hi);
            btH[(k*QC + q)*DC + t] = hi;
            btL[(k*QC + q)*DC + t] = f2bf(gs - hf);
        }
    }
    __syncthreads();
    if (t < QC) {       // h = G mu
        float s = 0.f;
        for (int d = 0; d < DC; d++)
            s = fmaf(GT[t*129 + d], muS[d], s);
        hS[t] = s;
        float hh = s*s;
        hh += __shfl_xor(hh, 1, 16);
        hh += __shfl_xor(hh, 2, 16);
        hh += __shfl_xor(hh, 4, 16);
        hh += __shfl_xor(hh, 8, 16);
        if (t == 0) hhS = hh;
    }
    {
        float a = lp, b2 = ipm;
#pragma unroll
        for (int off = 1; off < 64; off <<= 1) {
            a  += __shfl_xor(a, off, 64);
            b2 += __shfl_xor(b2, off, 64);
        }
        if (t == 0)  { redS[0] = a; redS[1] = b2; }
        if (t == 64) { redS[2] = a; redS[3] = b2; }
    }
    __syncthreads();
    if (t < DC) {       // w' = invpsi*mu - G^T h
        float gh = 0.f;
#pragma unroll
        for (int q = 0; q < QC; q++) gh = fmaf(g[q], hS[q], gh);
        float wp = invpsiS[t]*muS[t] - gh;
        short hi = f2bf(wp);
        float hf = bf2f(hi);
        btH[(512 + k)*DC + t] = hi;
        btL[(512 + k)*DC + t] = f2bf(wp - hf);
    }
    if (t == 0) {
        const float log2pi = 1.8378770664093453f;
        float slp = redS[0] + redS[2];
        float tv  = redS[1] + redS[3];
        c2p[k] = log_pi[k]
            - 0.5f*((float)DC*log2pi + slp + ldS + tv) + 0.5f*hhS;
    }
}

// ---------------------------------------------------------------------------
// Kernel 2: MFMA GEMM. 2504 linear blocks; yb = wg&7 (XCD-affine comp group
// of 4), xb = wg>>3 (64-row tile). Block = 4 waves, each 16 rows x 5 N-tiles.
// LDS exactly 40KB (80 rows x 256B x hi/lo planes, XOR-swizzled); rows 68..79
// stage harmless real data read only into never-extracted pacc columns.
// lr = C2' + w'.x - 0.5 s2 + ||(G/sqrt2) x||^2   (0.5s2 precomputed).
// ---------------------------------------------------------------------------
#define LH (80*256)      // 20480 bytes per plane

__global__ __launch_bounds__(256, 4) void mfa_gemm(
    const short* __restrict__ xH, const short* __restrict__ xL,
    const float* __restrict__ s2g, const float* __restrict__ c2p,
    const short* __restrict__ btH, const short* __restrict__ btL,
    float* __restrict__ out)
{
    __shared__ __align__(16) char lds[2*LH];     // 40960 B
    int t = threadIdx.x;
    int wg = blockIdx.x;
    int yb = wg & 7, xb = wg >> 3;

    // stage: 5 static iterations/thread; all loads issued before writes
    bf16x8 rh[5], rl[5];
#pragma unroll
    for (int i = 0; i < 5; i++) {
        int s = t + i*256;
        int row = s >> 4, seg = s & 15;
        int gr = (row < 64) ? (yb*64 + row) : (512 + yb*4 + ((row - 64) & 3));
        rh[i] = *(const bf16x8*)(btH + gr*DC + seg*8);
        rl[i] = *(const bf16x8*)(btL + gr*DC + seg*8);
    }

    int l = t & 63, w = t >> 6;
    int m16 = l & 15, g4 = l >> 4;
    int rb0 = xb*64 + w*16;
    int xr = min(rb0 + m16, NPTS - 1);

    // A fragments (precomputed bf16 hi/lo) + 0.5*s2
    bf16x8 aH[4], aL[4];
    const short* ph = xH + (size_t)xr*DC + g4*8;
    const short* pl = xL + (size_t)xr*DC + g4*8;
#pragma unroll
    for (int ks = 0; ks < 4; ks++) {
        aH[ks] = *(const bf16x8*)(ph + ks*32);
        aL[ks] = *(const bf16x8*)(pl + ks*32);
    }
    float s2p = s2g[xr];

#pragma unroll
    for (int i = 0; i < 5; i++) {
        int s = t + i*256;
        int row = s >> 4, seg = s & 15;
        unsigned bo = ((unsigned)(row*256 + seg*16)) ^ ((unsigned)(row & 7) << 4);
        *(bf16x8*)(lds + bo)      = rh[i];
        *(bf16x8*)(lds + LH + bo) = rl[i];
    }
    __syncthreads();

    f32x4 acc[5];
#pragma unroll
    for (int i = 0; i < 5; i++) acc[i] = (f32x4){0.f, 0.f, 0.f, 0.f};
#pragma unroll
    for (int nt = 0; nt < 5; nt++) {
        int row = (nt < 4 ? nt*16 : 64) + m16;
        unsigned rbse = (unsigned)row << 8;
        unsigned sw = (unsigned)(row & 7) << 4;
#pragma unroll
        for (int ks = 0; ks < 4; ks++) {
            unsigned bo = (rbse + (unsigned)((ks*32 + g4*8)*2)) ^ sw;
            bf16x8 bh = *(const bf16x8*)(lds + bo);
            bf16x8 bl = *(const bf16x8*)(lds + LH + bo);
            acc[nt] = __builtin_amdgcn_mfma_f32_16x16x32_bf16(aH[ks], bh, acc[nt], 0, 0, 0);
            acc[nt] = __builtin_amdgcn_mfma_f32_16x16x32_bf16(aL[ks], bh, acc[nt], 0, 0, 0);
            acc[nt] = __builtin_amdgcn_mfma_f32_16x16x32_bf16(aH[ks], bl, acc[nt], 0, 0, 0);
        }
    }

#pragma unroll
    for (int nt = 0; nt < 4; nt++) {
        float c2v = c2p[yb*4 + nt];
#pragma unroll
        for (int j = 0; j < 4; j++) {
            float v = acc[nt][j]*acc[nt][j];
            v += __shfl_xor(v, 1, 64);
            v += __shfl_xor(v, 2, 64);
            v += __shfl_xor(v, 4, 64);
            v += __shfl_xor(v, 8, 64);                 // sum over q
            float pv  = __shfl(acc[4][j], (l & 48) | nt, 64);
            float s2j = __shfl(s2p, (l & 48) | (g4*4 + j), 64);
            float lr = c2v + pv - s2j + v;
            int row = rb0 + g4*4 + j;
            if (m16 == 0 && row < NPTS)
                out[(size_t)row*KC + yb*4 + nt] = lr;
        }
    }
}

// ---------------------------------------------------------------------------
// Kernel 3: in-place logsumexp normalize + log-likelihood output.
// ---------------------------------------------------------------------------
__global__ __launch_bounds__(256) void mfa_norm(float* __restrict__ out)
{
    int n = blockIdx.x * 256 + threadIdx.x;
    if (n >= NPTS) return;
    float lr[KC];
#pragma unroll
    for (int i = 0; i < 8; i++)
        *(float4*)&lr[i*4] = *(const float4*)(out + (size_t)n*KC + i*4);
    float m = -1e30f;
#pragma unroll
    for (int k = 0; k < KC; k++) m = fmaxf(m, lr[k]);
    float s = 0.0f;
#pragma unroll
    for (int k = 0; k < KC; k++) s += expf(lr[k] - m);
    float ll = m + logf(s);
#pragma unroll
    for (int k = 0; k < KC; k++) lr[k] -= ll;
#pragma unroll
    for (int i = 0; i < 8; i++)
        *(float4*)(out + (size_t)n*KC + i*4) = *(const float4*)&lr[i*4];
    out[(size_t)NPTS*KC + n] = ll;
}

extern "C" void kernel_launch(void* const* d_in, const int* in_sizes, int n_in,
                              void* d_out, int out_size, void* d_ws, size_t ws_size,
                              hipStream_t stream)
{
    const float* X       = (const float*)d_in[0];
    const float* log_pi  = (const float*)d_in[1];
    const float* mu      = (const float*)d_in[2];
    const float* Lam     = (const float*)d_in[3];
    const float* log_psi = (const float*)d_in[4];
    float* out = (float*)d_out;
    char* wsb = (char*)d_ws;
    float* c2p = (float*)(wsb + WS_C2P_B);
    short* btH = (short*)(wsb + WS_BTH_B);
    short* btL = (short*)(wsb + WS_BTL_B);
    short* xH  = (short*)(wsb + WS_XH_B);
    short* xL  = (short*)(wsb + WS_XL_B);
    float* s2g = (float*)(wsb + WS_S2_B);

    hipLaunchKernelGGL(mfa_prep, dim3(KC + 314), dim3(256), 0, stream,
                       X, log_pi, mu, Lam, log_psi, c2p, btH, btL, xH, xL, s2g);
    hipLaunchKernelGGL(mfa_gemm, dim3(2504), dim3(256), 0, stream,
                       xH, xL, s2g, c2p, btH, btL, out);
    hipLaunchKernelGGL(mfa_norm, dim3(79), dim3(256), 0, stream, out);
}